// Round 1
// baseline (1466.546 us; speedup 1.0000x reference)
//
#include <hip/hip_runtime.h>
#include <math.h>

#define NB 4
#define SEQ 8192
#define NT (NB*SEQ)        // 32768 tokens
#define HDIM 64
#define NST 16
#define NBLK 4
#define KCONV 16
#define DIN 128
#define PDIM 16            // head dim
#define NH 8
#define CDIM 160
#define EPROJ 296
#define CH 128             // chunk length
#define NC 64              // chunks per sequence

__device__ __forceinline__ float sigf(float x){ return 1.0f/(1.0f+__expf(-x)); }

// h[t][d] = x[t] * w_in[d]
__global__ __launch_bounds__(256) void k_init_h(const float* __restrict__ x, const float* __restrict__ w_in,
                                                float* __restrict__ h){
  int i = blockIdx.x*256 + threadIdx.x;
  int t = i >> 6, d = i & 63;
  h[i] = x[t]*w_in[d];
}

// zx[e][t] = sum_d h[t][d] * w[e][d]   (channel-major output)
__global__ __launch_bounds__(256) void k_inproj(const float* __restrict__ h, const float* __restrict__ w,
                                                float* __restrict__ zx){
  int tok = blockIdx.x*64 + (threadIdx.x & 63);
  int eg = threadIdx.x >> 6;
  float4 hr[16];
  const float4* hp = (const float4*)(h + tok*HDIM);
#pragma unroll
  for(int i=0;i<16;i++) hr[i] = hp[i];
  for(int e = eg; e < EPROJ; e += 4){
    const float4* wr = (const float4*)(w + e*HDIM);
    float acc = 0.f;
#pragma unroll
    for(int i=0;i<16;i++){
      float4 wv = wr[i];
      acc += hr[i].x*wv.x + hr[i].y*wv.y + hr[i].z*wv.z + hr[i].w*wv.w;
    }
    zx[e*NT + tok] = acc;
  }
}

// depthwise causal conv over l (16 taps) + bias + silu; input = zx channels [DIN, DIN+CDIM)
__global__ __launch_bounds__(256) void k_conv(const float* __restrict__ zx, const float* __restrict__ cw,
                                              const float* __restrict__ cb, float* __restrict__ xbc){
  int c = blockIdx.x >> 7;          // NT/256 = 128 tiles
  int t = (blockIdx.x & 127)*256 + threadIdx.x;
  int l = t & (SEQ-1);
  const float* in = zx + (DIN + c)*NT;
  float acc = cb[c];
#pragma unroll
  for(int k=0;k<KCONV;k++){
    int ll = l - (KCONV-1) + k;
    float v = (ll >= 0) ? in[t - (KCONV-1) + k] : 0.f;
    acc += cw[c*KCONV + k] * v;
  }
  xbc[c*NT + t] = acc * sigf(acc);
}

// dt[hh][t] = softplus(zx[288+hh][t] + dt_bias[hh])
__global__ __launch_bounds__(256) void k_dt(const float* __restrict__ zx, const float* __restrict__ dtb,
                                            float* __restrict__ dt){
  int hh = blockIdx.x >> 7;
  int t = (blockIdx.x & 127)*256 + threadIdx.x;
  float raw = zx[(DIN + CDIM + hh)*NT + t] + dtb[hh];
  dt[hh*NT + t] = (raw > 20.f) ? raw : log1pf(__expf(raw));
}

// per-(b,chunk,head): inclusive cumsum of dA = dt*A within chunk; store acs + chunk total asum
__global__ __launch_bounds__(64) void k_cumsum(const float* __restrict__ dt, const float* __restrict__ alog,
                                               float* __restrict__ acs, float* __restrict__ asum){
  int hh = blockIdx.x & 7;
  int c  = (blockIdx.x >> 3) & 63;
  int b  = blockIdx.x >> 9;
  int lane = threadIdx.x;
  int t0 = b*SEQ + c*CH;
  float A = -__expf(alog[hh]);
  float2 d2 = *(const float2*)(dt + hh*NT + t0 + 2*lane);
  float v0 = d2.x*A, v1 = d2.y*A;
  float s = v0 + v1;
  for(int off=1; off<64; off<<=1){
    float o = __shfl_up(s, off);
    if(lane >= off) s += o;
  }
  float excl = s - (v0+v1);
  *(float2*)(acs + hh*NT + t0 + 2*lane) = make_float2(excl+v0, excl+v0+v1);
  if(lane == 63) asum[(b*NC + c)*NH + hh] = s;
}

// chunk states S[b,c,h,p,n] = sum_s B[s,n] * xs[s,h,p] * dt[s] * exp(asum - acs[s])
__global__ __launch_bounds__(256) void k_states(const float* __restrict__ xbc, const float* __restrict__ dt,
                                                const float* __restrict__ acs, const float* __restrict__ asum,
                                                float* __restrict__ S){
  int hh = blockIdx.x & 7;
  int c  = (blockIdx.x >> 3) & 63;
  int b  = blockIdx.x >> 9;
  int t0 = b*SEQ + c*CH;
  __shared__ float Bl[CH][NST+4];
  __shared__ float Xl[CH][PDIM+4];
  __shared__ float Wl[CH];
  int tid = threadIdx.x;
#pragma unroll
  for(int r=0;r<8;r++){
    int idx = tid + r*256;
    int s = idx & 127, n = idx >> 7;
    Bl[s][n] = xbc[(DIN + n)*NT + t0 + s];
    Xl[s][n] = xbc[(hh*PDIM + n)*NT + t0 + s];
  }
  if(tid < 128){
    float as = asum[(b*NC + c)*NH + hh];
    Wl[tid] = dt[hh*NT + t0 + tid] * __expf(as - acs[hh*NT + t0 + tid]);
  }
  __syncthreads();
  int n = tid & 15, p = tid >> 4;
  float acc = 0.f;
#pragma unroll 4
  for(int s=0;s<CH;s++) acc += Bl[s][n] * (Xl[s][p] * Wl[s]);
  S[((b*NC + c)*NH + hh)*256 + tid] = acc;
}

// sequential scan over 64 chunks: prev[c] = state entering chunk c
__global__ __launch_bounds__(256) void k_scan(const float* __restrict__ S, const float* __restrict__ asum,
                                              const float* __restrict__ init, float* __restrict__ prev){
  int hh = blockIdx.x & 7;
  int b  = blockIdx.x >> 3;
  int tid = threadIdx.x;
  float r = init[hh*256 + tid];
  for(int c=0;c<NC;c++){
    int base = ((b*NC + c)*NH + hh)*256;
    prev[base + tid] = r;
    r = __expf(asum[(b*NC + c)*NH + hh])*r + S[base + tid];
  }
}

// per-(b,chunk,head): Y = (tril(C B^T * decay * dt) X + C prev^T exp(acs) + D*xs) * silu(z)
__global__ __launch_bounds__(128) void k_y(const float* __restrict__ xbc, const float* __restrict__ zx,
                                           const float* __restrict__ dt, const float* __restrict__ acs,
                                           const float* __restrict__ prev, const float* __restrict__ dskip,
                                           float* __restrict__ y){
  int hh = blockIdx.x & 7;
  int c  = (blockIdx.x >> 3) & 63;
  int b  = blockIdx.x >> 9;
  int t0 = b*SEQ + c*CH;
  __shared__ __align__(16) float Bl[CH][NST+4];
  __shared__ __align__(16) float Xl[CH][PDIM+4];
  __shared__ float Al[CH];
  __shared__ float Dtl[CH];
  __shared__ float Pl[256];
  int tid = threadIdx.x;
#pragma unroll
  for(int r=0;r<16;r++){
    Bl[tid][r] = xbc[(DIN + r)*NT + t0 + tid];
    Xl[tid][r] = xbc[(hh*PDIM + r)*NT + t0 + tid];
  }
  Al[tid]  = acs[hh*NT + t0 + tid];
  Dtl[tid] = dt[hh*NT + t0 + tid];
  {
    int pb = ((b*NC + c)*NH + hh)*256;
    Pl[tid]     = prev[pb + tid];
    Pl[tid+128] = prev[pb + tid + 128];
  }
  __syncthreads();
  int l = tid;
  float C[16];
#pragma unroll
  for(int n=0;n<16;n++) C[n] = xbc[(DIN+NST+n)*NT + t0 + l];
  float a_l = Al[l];
  float acc[16];
#pragma unroll
  for(int p=0;p<16;p++) acc[p]=0.f;
  for(int s=0;s<=l;s++){
    const float4* bp = (const float4*)&Bl[s][0];
    float4 b0=bp[0], b1=bp[1], b2=bp[2], b3=bp[3];
    float dots = C[0]*b0.x + C[1]*b0.y + C[2]*b0.z + C[3]*b0.w
               + C[4]*b1.x + C[5]*b1.y + C[6]*b1.z + C[7]*b1.w
               + C[8]*b2.x + C[9]*b2.y + C[10]*b2.z + C[11]*b2.w
               + C[12]*b3.x + C[13]*b3.y + C[14]*b3.z + C[15]*b3.w;
    float w = dots * __expf(a_l - Al[s]) * Dtl[s];
    const float4* xp = (const float4*)&Xl[s][0];
    float4 x0=xp[0], x1=xp[1], x2=xp[2], x3=xp[3];
    acc[0] +=w*x0.x; acc[1] +=w*x0.y; acc[2] +=w*x0.z; acc[3] +=w*x0.w;
    acc[4] +=w*x1.x; acc[5] +=w*x1.y; acc[6] +=w*x1.z; acc[7] +=w*x1.w;
    acc[8] +=w*x2.x; acc[9] +=w*x2.y; acc[10]+=w*x2.z; acc[11]+=w*x2.w;
    acc[12]+=w*x3.x; acc[13]+=w*x3.y; acc[14]+=w*x3.z; acc[15]+=w*x3.w;
  }
  float ea = __expf(a_l);
#pragma unroll
  for(int p=0;p<16;p++){
    float ts = 0.f;
#pragma unroll
    for(int n=0;n<16;n++) ts += C[n]*Pl[p*16+n];
    acc[p] += ea*ts;
  }
  float Dk = dskip[hh];
#pragma unroll
  for(int p=0;p<16;p++){
    float zv = zx[(hh*PDIM + p)*NT + t0 + l];
    float g = zv * sigf(zv);
    acc[p] = (acc[p] + Dk*Xl[l][p]) * g;
  }
  float4* yo = (float4*)(y + (t0+l)*DIN + hh*PDIM);
  yo[0] = make_float4(acc[0], acc[1], acc[2], acc[3]);
  yo[1] = make_float4(acc[4], acc[5], acc[6], acc[7]);
  yo[2] = make_float4(acc[8], acc[9], acc[10],acc[11]);
  yo[3] = make_float4(acc[12],acc[13],acc[14],acc[15]);
}

// RMSNorm(y) -> out_proj(64x128) -> softsign -> mlp(64x64)+bias -> h += ; one wave per token
__global__ __launch_bounds__(256) void k_out(const float* __restrict__ y, const float* __restrict__ nw,
                                             const float* __restrict__ opw, const float* __restrict__ mw,
                                             const float* __restrict__ mb, float* __restrict__ h){
  int wave = threadIdx.x >> 6;
  int lane = threadIdx.x & 63;
  int t = blockIdx.x*4 + wave;
  __shared__ __align__(16) float nbuf[4][DIN];
  __shared__ __align__(16) float tbuf[4][HDIM];
  float y0 = y[t*DIN + lane];
  float y1 = y[t*DIN + 64 + lane];
  float ss = y0*y0 + y1*y1;
  for(int off=32; off>0; off>>=1) ss += __shfl_xor(ss, off);
  float rms = rsqrtf(ss*(1.0f/DIN) + 1e-5f);
  nbuf[wave][lane]    = y0*rms*nw[lane];
  nbuf[wave][64+lane] = y1*rms*nw[64+lane];
  __syncthreads();
  float o = 0.f;
  const float4* wr = (const float4*)(opw + lane*DIN);
  const float4* nb = (const float4*)nbuf[wave];
#pragma unroll
  for(int i=0;i<32;i++){
    float4 wv = wr[i]; float4 nv = nb[i];
    o += wv.x*nv.x + wv.y*nv.y + wv.z*nv.z + wv.w*nv.w;
  }
  float tv = o * rsqrtf(1.0f + o*o);
  tbuf[wave][lane] = tv;
  __syncthreads();
  float m = mb[lane];
  const float4* mr = (const float4*)(mw + lane*HDIM);
  const float4* tb = (const float4*)tbuf[wave];
#pragma unroll
  for(int i=0;i<16;i++){
    float4 wv = mr[i]; float4 tq = tb[i];
    m += wv.x*tq.x + wv.y*tq.y + wv.z*tq.z + wv.w*tq.w;
  }
  h[t*HDIM + lane] += m;
}

__global__ __launch_bounds__(256) void k_final(const float* __restrict__ h, const float* __restrict__ wout,
                                               float* __restrict__ out){
  int t = blockIdx.x*256 + threadIdx.x;
  const float4* hp = (const float4*)(h + t*HDIM);
  float acc = 0.f;
#pragma unroll
  for(int i=0;i<16;i++){
    float4 hv = hp[i]; float4 wv = ((const float4*)wout)[i];
    acc += hv.x*wv.x + hv.y*wv.y + hv.z*wv.z + hv.w*wv.w;
  }
  out[t] = acc;
}

extern "C" void kernel_launch(void* const* d_in, const int* in_sizes, int n_in,
                              void* d_out, int out_size, void* d_ws, size_t ws_size,
                              hipStream_t stream){
  const float* x          = (const float*)d_in[0];
  const float* w_in       = (const float*)d_in[1];
  const float* w_out      = (const float*)d_in[2];
  const float* in_proj_w  = (const float*)d_in[3];
  const float* conv_w     = (const float*)d_in[4];
  const float* conv_b     = (const float*)d_in[5];
  const float* dt_bias    = (const float*)d_in[6];
  const float* A_log      = (const float*)d_in[7];
  const float* D_skip     = (const float*)d_in[8];
  const float* init_st    = (const float*)d_in[9];
  const float* norm_w     = (const float*)d_in[10];
  const float* out_proj_w = (const float*)d_in[11];
  const float* mlp_w      = (const float*)d_in[12];
  const float* mlp_b      = (const float*)d_in[13];
  float* out = (float*)d_out;

  float* ws = (float*)d_ws;
  float* h    = ws; ws += (size_t)NT*HDIM;
  float* zx   = ws; ws += (size_t)EPROJ*NT;
  float* xbc  = ws; ws += (size_t)CDIM*NT;
  float* dt   = ws; ws += (size_t)NH*NT;
  float* acs  = ws; ws += (size_t)NH*NT;
  float* asum = ws; ws += (size_t)NB*NC*NH;
  float* S    = ws; ws += (size_t)NB*NC*NH*256;
  float* prev = ws; ws += (size_t)NB*NC*NH*256;
  float* y    = ws; ws += (size_t)NT*DIN;

  k_init_h<<<(NT*HDIM)/256, 256, 0, stream>>>(x, w_in, h);
  for(int i=0;i<NBLK;i++){
    k_inproj<<<NT/64, 256, 0, stream>>>(h, in_proj_w + i*EPROJ*HDIM, zx);
    k_conv  <<<CDIM*(NT/256), 256, 0, stream>>>(zx, conv_w + i*CDIM*KCONV, conv_b + i*CDIM, xbc);
    k_dt    <<<NH*(NT/256), 256, 0, stream>>>(zx, dt_bias + i*NH, dt);
    k_cumsum<<<NB*NC*NH, 64, 0, stream>>>(dt, A_log + i*NH, acs, asum);
    k_states<<<NB*NC*NH, 256, 0, stream>>>(xbc, dt, acs, asum, S);
    k_scan  <<<NB*NH, 256, 0, stream>>>(S, asum, init_st + i*NH*256, prev);
    k_y     <<<NB*NC*NH, 128, 0, stream>>>(xbc, zx, dt, acs, prev, D_skip + i*NH, y);
    k_out   <<<NT/4, 256, 0, stream>>>(y, norm_w + i*DIN, out_proj_w + i*HDIM*DIN,
                                       mlp_w + i*HDIM*HDIM, mlp_b + i*HDIM, h);
  }
  k_final<<<NT/256, 256, 0, stream>>>(h, w_out, out);
}

// Round 2
// 875.929 us; speedup vs baseline: 1.6743x; 1.6743x over previous
//
#include <hip/hip_runtime.h>
#include <math.h>

#define NB 4
#define SEQ 8192
#define NT (NB*SEQ)        // 32768 tokens
#define HDIM 64
#define NST 16
#define NBLK 4
#define KCONV 16
#define DIN 128
#define PDIM 16            // head dim
#define NH 8
#define CDIM 160
#define EPROJ 296
#define CH 128             // chunk length
#define NC 64              // chunks per sequence

__device__ __forceinline__ float sigf(float x){ return 1.0f/(1.0f+__expf(-x)); }

// h[t][d] = x[t] * w_in[d]
__global__ __launch_bounds__(256) void k_init_h(const float* __restrict__ x, const float* __restrict__ w_in,
                                                float* __restrict__ h){
  int i = blockIdx.x*256 + threadIdx.x;
  int t = i >> 6, d = i & 63;
  h[i] = x[t]*w_in[d];
}

// zx[e][t] = sum_d h[t][d] * w[e][d]   (channel-major output)
__global__ __launch_bounds__(256) void k_inproj(const float* __restrict__ h, const float* __restrict__ w,
                                                float* __restrict__ zx){
  int tok = blockIdx.x*64 + (threadIdx.x & 63);
  int eg = threadIdx.x >> 6;
  float4 hr[16];
  const float4* hp = (const float4*)(h + tok*HDIM);
#pragma unroll
  for(int i=0;i<16;i++) hr[i] = hp[i];
  for(int e = eg; e < EPROJ; e += 4){
    const float4* wr = (const float4*)(w + e*HDIM);
    float acc = 0.f;
#pragma unroll
    for(int i=0;i<16;i++){
      float4 wv = wr[i];
      acc += hr[i].x*wv.x + hr[i].y*wv.y + hr[i].z*wv.z + hr[i].w*wv.w;
    }
    zx[e*NT + tok] = acc;
  }
}

// depthwise causal conv over l (16 taps) + bias + silu; input = zx channels [DIN, DIN+CDIM)
__global__ __launch_bounds__(256) void k_conv(const float* __restrict__ zx, const float* __restrict__ cw,
                                              const float* __restrict__ cb, float* __restrict__ xbc){
  int c = blockIdx.x >> 7;          // NT/256 = 128 tiles
  int t = (blockIdx.x & 127)*256 + threadIdx.x;
  int l = t & (SEQ-1);
  const float* in = zx + (DIN + c)*NT;
  float acc = cb[c];
#pragma unroll
  for(int k=0;k<KCONV;k++){
    int ll = l - (KCONV-1) + k;
    float v = (ll >= 0) ? in[t - (KCONV-1) + k] : 0.f;
    acc += cw[c*KCONV + k] * v;
  }
  xbc[c*NT + t] = acc * sigf(acc);
}

// dt[hh][t] = softplus(zx[288+hh][t] + dt_bias[hh])
__global__ __launch_bounds__(256) void k_dt(const float* __restrict__ zx, const float* __restrict__ dtb,
                                            float* __restrict__ dt){
  int hh = blockIdx.x >> 7;
  int t = (blockIdx.x & 127)*256 + threadIdx.x;
  float raw = zx[(DIN + CDIM + hh)*NT + t] + dtb[hh];
  dt[hh*NT + t] = (raw > 20.f) ? raw : log1pf(__expf(raw));
}

// per-(b,chunk,head): inclusive cumsum of dA = dt*A within chunk; store acs + chunk total asum
__global__ __launch_bounds__(64) void k_cumsum(const float* __restrict__ dt, const float* __restrict__ alog,
                                               float* __restrict__ acs, float* __restrict__ asum){
  int hh = blockIdx.x & 7;
  int c  = (blockIdx.x >> 3) & 63;
  int b  = blockIdx.x >> 9;
  int lane = threadIdx.x;
  int t0 = b*SEQ + c*CH;
  float A = -__expf(alog[hh]);
  float2 d2 = *(const float2*)(dt + hh*NT + t0 + 2*lane);
  float v0 = d2.x*A, v1 = d2.y*A;
  float s = v0 + v1;
  for(int off=1; off<64; off<<=1){
    float o = __shfl_up(s, off);
    if(lane >= off) s += o;
  }
  float excl = s - (v0+v1);
  *(float2*)(acs + hh*NT + t0 + 2*lane) = make_float2(excl+v0, excl+v0+v1);
  if(lane == 63) asum[(b*NC + c)*NH + hh] = s;
}

// chunk states S[b,c,h,p,n] = sum_s B[s,n] * xs[s,h,p] * dt[s] * exp(asum - acs[s])
__global__ __launch_bounds__(256) void k_states(const float* __restrict__ xbc, const float* __restrict__ dt,
                                                const float* __restrict__ acs, const float* __restrict__ asum,
                                                float* __restrict__ S){
  int hh = blockIdx.x & 7;
  int c  = (blockIdx.x >> 3) & 63;
  int b  = blockIdx.x >> 9;
  int t0 = b*SEQ + c*CH;
  __shared__ float Bl[CH][NST+4];
  __shared__ float Xl[CH][PDIM+4];
  __shared__ float Wl[CH];
  int tid = threadIdx.x;
#pragma unroll
  for(int r=0;r<8;r++){
    int idx = tid + r*256;
    int s = idx & 127, n = idx >> 7;
    Bl[s][n] = xbc[(DIN + n)*NT + t0 + s];
    Xl[s][n] = xbc[(hh*PDIM + n)*NT + t0 + s];
  }
  if(tid < 128){
    float as = asum[(b*NC + c)*NH + hh];
    Wl[tid] = dt[hh*NT + t0 + tid] * __expf(as - acs[hh*NT + t0 + tid]);
  }
  __syncthreads();
  int n = tid & 15, p = tid >> 4;
  float acc = 0.f;
#pragma unroll 4
  for(int s=0;s<CH;s++) acc += Bl[s][n] * (Xl[s][p] * Wl[s]);
  S[((b*NC + c)*NH + hh)*256 + tid] = acc;
}

// sequential scan over 64 chunks: prev[c] = state entering chunk c
__global__ __launch_bounds__(256) void k_scan(const float* __restrict__ S, const float* __restrict__ asum,
                                              const float* __restrict__ init, float* __restrict__ prev){
  int hh = blockIdx.x & 7;
  int b  = blockIdx.x >> 3;
  int tid = threadIdx.x;
  float r = init[hh*256 + tid];
  for(int c=0;c<NC;c++){
    int base = ((b*NC + c)*NH + hh)*256;
    prev[base + tid] = r;
    r = __expf(asum[(b*NC + c)*NH + hh])*r + S[base + tid];
  }
}

// per-(b,chunk,head): Y = (tril(C B^T * decay * dt) X + C prev^T exp(acs) + D*xs) * silu(z)
__global__ __launch_bounds__(128) void k_y(const float* __restrict__ xbc, const float* __restrict__ zx,
                                           const float* __restrict__ dt, const float* __restrict__ acs,
                                           const float* __restrict__ prev, const float* __restrict__ dskip,
                                           float* __restrict__ y){
  int hh = blockIdx.x & 7;
  int c  = (blockIdx.x >> 3) & 63;
  int b  = blockIdx.x >> 9;
  int t0 = b*SEQ + c*CH;
  __shared__ __align__(16) float Bl[CH][NST+4];
  __shared__ __align__(16) float Xl[CH][PDIM+4];
  __shared__ float Al[CH];
  __shared__ float Dtl[CH];
  __shared__ float Pl[256];
  int tid = threadIdx.x;
#pragma unroll
  for(int r=0;r<16;r++){
    Bl[tid][r] = xbc[(DIN + r)*NT + t0 + tid];
    Xl[tid][r] = xbc[(hh*PDIM + r)*NT + t0 + tid];
  }
  Al[tid]  = acs[hh*NT + t0 + tid];
  Dtl[tid] = dt[hh*NT + t0 + tid];
  {
    int pb = ((b*NC + c)*NH + hh)*256;
    Pl[tid]     = prev[pb + tid];
    Pl[tid+128] = prev[pb + tid + 128];
  }
  __syncthreads();
  int l = tid;
  float C[16];
#pragma unroll
  for(int n=0;n<16;n++) C[n] = xbc[(DIN+NST+n)*NT + t0 + l];
  float a_l = Al[l];
  float acc[16];
#pragma unroll
  for(int p=0;p<16;p++) acc[p]=0.f;
  for(int s=0;s<=l;s++){
    const float4* bp = (const float4*)&Bl[s][0];
    float4 b0=bp[0], b1=bp[1], b2=bp[2], b3=bp[3];
    float dots = C[0]*b0.x + C[1]*b0.y + C[2]*b0.z + C[3]*b0.w
               + C[4]*b1.x + C[5]*b1.y + C[6]*b1.z + C[7]*b1.w
               + C[8]*b2.x + C[9]*b2.y + C[10]*b2.z + C[11]*b2.w
               + C[12]*b3.x + C[13]*b3.y + C[14]*b3.z + C[15]*b3.w;
    float w = dots * __expf(a_l - Al[s]) * Dtl[s];
    const float4* xp = (const float4*)&Xl[s][0];
    float4 x0=xp[0], x1=xp[1], x2=xp[2], x3=xp[3];
    acc[0] +=w*x0.x; acc[1] +=w*x0.y; acc[2] +=w*x0.z; acc[3] +=w*x0.w;
    acc[4] +=w*x1.x; acc[5] +=w*x1.y; acc[6] +=w*x1.z; acc[7] +=w*x1.w;
    acc[8] +=w*x2.x; acc[9] +=w*x2.y; acc[10]+=w*x2.z; acc[11]+=w*x2.w;
    acc[12]+=w*x3.x; acc[13]+=w*x3.y; acc[14]+=w*x3.z; acc[15]+=w*x3.w;
  }
  float ea = __expf(a_l);
#pragma unroll
  for(int p=0;p<16;p++){
    float ts = 0.f;
#pragma unroll
    for(int n=0;n<16;n++) ts += C[n]*Pl[p*16+n];
    acc[p] += ea*ts;
  }
  float Dk = dskip[hh];
#pragma unroll
  for(int p=0;p<16;p++){
    float zv = zx[(hh*PDIM + p)*NT + t0 + l];
    float g = zv * sigf(zv);
    acc[p] = (acc[p] + Dk*Xl[l][p]) * g;
  }
  float4* yo = (float4*)(y + (t0+l)*DIN + hh*PDIM);
  yo[0] = make_float4(acc[0], acc[1], acc[2], acc[3]);
  yo[1] = make_float4(acc[4], acc[5], acc[6], acc[7]);
  yo[2] = make_float4(acc[8], acc[9], acc[10],acc[11]);
  yo[3] = make_float4(acc[12],acc[13],acc[14],acc[15]);
}

// RMSNorm(y) -> out_proj(64x128) -> softsign -> mlp(64x64)+bias -> h +=
// LDS-tiled GEMM: 32 tokens per 256-thread block; weights staged once per block.
// LDS reads in GEMM phases are <=2-way bank aliased (free per m136).
__global__ __launch_bounds__(256) void k_out(const float* __restrict__ y, const float* __restrict__ nw,
                                             const float* __restrict__ opw, const float* __restrict__ mw,
                                             const float* __restrict__ mb, float* __restrict__ h){
  __shared__ float ss[32];
  __shared__ float nwl[128];
  __shared__ float mbl[64];
  __shared__ __align__(16) float yt[32][132];   // 16896 B, row stride 528 B (16B-aligned)
  __shared__ __align__(16) float W[64][132];    // 33792 B; reused for mlp W2[64][68] + tb[32][68]
  int tid = threadIdx.x;
  int t0 = blockIdx.x * 32;
  int ln = tid & 63;

  if(tid < 128) nwl[tid] = nw[tid];
  else if(tid < 192) mbl[tid-128] = mb[tid-128];

  // stage y tile (coalesced float4) + per-token sum-of-squares via shuffle
  const float4* yg = (const float4*)(y + (size_t)t0*DIN);
#pragma unroll
  for(int k=0;k<4;k++){
    int fi = tid + k*256;          // float4 index 0..1023 (32 per token)
    float4 f = yg[fi];
    int tok = fi >> 5, c4 = fi & 31;
    *(float4*)&yt[tok][c4*4] = f;
    float d = f.x*f.x + f.y*f.y + f.z*f.z + f.w*f.w;
    d += __shfl_xor(d, 1); d += __shfl_xor(d, 2); d += __shfl_xor(d, 4);
    d += __shfl_xor(d, 8); d += __shfl_xor(d, 16);
    if((ln & 31) == 0) ss[tok] = d;
  }
  // stage out_proj weights 64x128 (coalesced)
  const float4* wg = (const float4*)opw;
#pragma unroll
  for(int k=0;k<8;k++){
    int fi = tid + k*256;          // 0..2047
    int r = fi >> 5, c4 = fi & 31;
    *(float4*)&W[r][c4*4] = wg[fi];
  }
  __syncthreads();

  // fold RMS scale + norm weight into yt
#pragma unroll
  for(int k=0;k<4;k++){
    int fi = tid + k*256;
    int tok = fi >> 5, c4 = fi & 31;
    float r = rsqrtf(ss[tok]*(1.0f/128.0f) + 1e-5f);
    float4 v = *(float4*)&yt[tok][c4*4];
    float4 wv = ((const float4*)nwl)[c4];
    v.x *= r*wv.x; v.y *= r*wv.y; v.z *= r*wv.z; v.w *= r*wv.w;
    *(float4*)&yt[tok][c4*4] = v;
  }
  __syncthreads();

  // GEMM1: out_proj. thread -> tokens {2tk,2tk+1}, outputs {to+16j}
  int to = tid & 15, tk = tid >> 4;
  float acc0[4] = {0,0,0,0}, acc1[4] = {0,0,0,0};
#pragma unroll
  for(int n4=0;n4<32;n4++){
    float4 x0 = *(const float4*)&yt[2*tk][n4*4];
    float4 x1 = *(const float4*)&yt[2*tk+1][n4*4];
#pragma unroll
    for(int j=0;j<4;j++){
      float4 wv = *(const float4*)&W[to + 16*j][n4*4];
      acc0[j] += x0.x*wv.x + x0.y*wv.y + x0.z*wv.z + x0.w*wv.w;
      acc1[j] += x1.x*wv.x + x1.y*wv.y + x1.z*wv.z + x1.w*wv.w;
    }
  }
  __syncthreads();   // GEMM1 done reading W/yt before region reuse

  // region reuse inside W: W2[64][68] at flat 0, tb[32][68] at flat 4352
  float* Wf = &W[0][0];
  float* tb = Wf + 4352;
#pragma unroll
  for(int j=0;j<4;j++){
    float o0 = acc0[j], o1 = acc1[j];
    tb[(2*tk)*68   + to + 16*j] = o0*rsqrtf(1.0f + o0*o0);
    tb[(2*tk+1)*68 + to + 16*j] = o1*rsqrtf(1.0f + o1*o1);
  }
  // stage mlp weights 64x64 (coalesced)
  const float4* mg = (const float4*)mw;
#pragma unroll
  for(int k=0;k<4;k++){
    int fi = tid + k*256;          // 0..1023
    int r = fi >> 4, c4 = fi & 15;
    *(float4*)&Wf[r*68 + c4*4] = mg[fi];
  }
  __syncthreads();

  // GEMM2: mlp
  float a20[4] = {0,0,0,0}, a21[4] = {0,0,0,0};
#pragma unroll
  for(int n4=0;n4<16;n4++){
    float4 x0 = *(const float4*)&tb[(2*tk)*68   + n4*4];
    float4 x1 = *(const float4*)&tb[(2*tk+1)*68 + n4*4];
#pragma unroll
    for(int j=0;j<4;j++){
      float4 wv = *(const float4*)&Wf[(to + 16*j)*68 + n4*4];
      a20[j] += x0.x*wv.x + x0.y*wv.y + x0.z*wv.z + x0.w*wv.w;
      a21[j] += x1.x*wv.x + x1.y*wv.y + x1.z*wv.z + x1.w*wv.w;
    }
  }
#pragma unroll
  for(int j=0;j<4;j++){
    int d = to + 16*j;
    float bias = mbl[d];
    h[(size_t)(t0 + 2*tk)*HDIM + d]     += a20[j] + bias;
    h[(size_t)(t0 + 2*tk + 1)*HDIM + d] += a21[j] + bias;
  }
}

__global__ __launch_bounds__(256) void k_final(const float* __restrict__ h, const float* __restrict__ wout,
                                               float* __restrict__ out){
  int t = blockIdx.x*256 + threadIdx.x;
  const float4* hp = (const float4*)(h + t*HDIM);
  float acc = 0.f;
#pragma unroll
  for(int i=0;i<16;i++){
    float4 hv = hp[i]; float4 wv = ((const float4*)wout)[i];
    acc += hv.x*wv.x + hv.y*wv.y + hv.z*wv.z + hv.w*wv.w;
  }
  out[t] = acc;
}

extern "C" void kernel_launch(void* const* d_in, const int* in_sizes, int n_in,
                              void* d_out, int out_size, void* d_ws, size_t ws_size,
                              hipStream_t stream){
  const float* x          = (const float*)d_in[0];
  const float* w_in       = (const float*)d_in[1];
  const float* w_out      = (const float*)d_in[2];
  const float* in_proj_w  = (const float*)d_in[3];
  const float* conv_w     = (const float*)d_in[4];
  const float* conv_b     = (const float*)d_in[5];
  const float* dt_bias    = (const float*)d_in[6];
  const float* A_log      = (const float*)d_in[7];
  const float* D_skip     = (const float*)d_in[8];
  const float* init_st    = (const float*)d_in[9];
  const float* norm_w     = (const float*)d_in[10];
  const float* out_proj_w = (const float*)d_in[11];
  const float* mlp_w      = (const float*)d_in[12];
  const float* mlp_b      = (const float*)d_in[13];
  float* out = (float*)d_out;

  float* ws = (float*)d_ws;
  float* h    = ws; ws += (size_t)NT*HDIM;
  float* zx   = ws; ws += (size_t)EPROJ*NT;
  float* xbc  = ws; ws += (size_t)CDIM*NT;
  float* dt   = ws; ws += (size_t)NH*NT;
  float* acs  = ws; ws += (size_t)NH*NT;
  float* asum = ws; ws += (size_t)NB*NC*NH;
  float* S    = ws; ws += (size_t)NB*NC*NH*256;
  float* prev = ws; ws += (size_t)NB*NC*NH*256;
  float* y    = ws; ws += (size_t)NT*DIN;

  k_init_h<<<(NT*HDIM)/256, 256, 0, stream>>>(x, w_in, h);
  for(int i=0;i<NBLK;i++){
    k_inproj<<<NT/64, 256, 0, stream>>>(h, in_proj_w + i*EPROJ*HDIM, zx);
    k_conv  <<<CDIM*(NT/256), 256, 0, stream>>>(zx, conv_w + i*CDIM*KCONV, conv_b + i*CDIM, xbc);
    k_dt    <<<NH*(NT/256), 256, 0, stream>>>(zx, dt_bias + i*NH, dt);
    k_cumsum<<<NB*NC*NH, 64, 0, stream>>>(dt, A_log + i*NH, acs, asum);
    k_states<<<NB*NC*NH, 256, 0, stream>>>(xbc, dt, acs, asum, S);
    k_scan  <<<NB*NH, 256, 0, stream>>>(S, asum, init_st + i*NH*256, prev);
    k_y     <<<NB*NC*NH, 128, 0, stream>>>(xbc, zx, dt, acs, prev, D_skip + i*NH, y);
    k_out   <<<NT/32, 256, 0, stream>>>(y, norm_w + i*DIN, out_proj_w + i*HDIM*DIN,
                                        mlp_w + i*HDIM*HDIM, mlp_b + i*HDIM, h);
  }
  k_final<<<NT/256, 256, 0, stream>>>(h, w_out, out);
}